// Round 2
// baseline (189.716 us; speedup 1.0000x reference)
//
#include <hip/hip_runtime.h>

// Problem constants (from reference)
#define B 64
#define H 128
#define W 128
#define R 4
#define GW 32
#define N 1024
#define D 16
#define S 32
// D*S = 512 output elements per n; each thread handles 4 -> 128 threads/block.
// Grid is (N, BCHUNKS): each block handles BSUB=16 of the 64 batch images.
// 4096 blocks x 2 waves = 32 waves/CU (100% occupancy) vs 25% in R1.
#define BSUB 16
#define BCHUNKS (B / BSUB)

__global__ __launch_bounds__(128) void conexao_regional_kernel(
    const float* __restrict__ x,       // [B,1,H,W]
    const float* __restrict__ pesos,   // [N,D,S,R,R]
    float* __restrict__ out)           // [B,N,D,S]
{
    __shared__ float sx[BSUB][R];  // patch diagonals for this block's (n, b-chunk)

    const int n   = blockIdx.x;
    const int b0  = blockIdx.y * BSUB;
    const int tid = threadIdx.x;

    // --- stage xd[b][r] = x[b, 0, i*R+r, j*R+r] into LDS (64 loads) ---
    // flat addr: b*H*W + (i*R)*W + j*R + r*(W+1)
    const int i = n / GW, j = n % GW;
    const int xbase = i * (R * W) + j * R;
    if (tid < BSUB * R) {
        const int bl = tid >> 2, r = tid & 3;
        sx[bl][r] = x[(b0 + bl) * (H * W) + xbase + r * (W + 1)];
    }
    __syncthreads();

    // --- load weight diagonals for this thread's 4 elements ---
    // pesos[n,d,s,:,:] is a contiguous 16-float (64 B) block at (n*512+e)*16;
    // diagonal elements sit at offsets 0, 5, 10, 15 within it.
    const int  e0    = tid * 4;                         // element in [0,512)
    const long pbase = ((long)n * 512 + e0) * 16;       // in floats
    float w[4][4];
#pragma unroll
    for (int k = 0; k < 4; ++k) {
        const float4* p = (const float4*)(pesos + pbase + (long)k * 16);
        const float4 q0 = p[0], q1 = p[1], q2 = p[2], q3 = p[3];
        w[k][0] = q0.x;  // [r=0][r=0] -> offset 0
        w[k][1] = q1.y;  // [1][1]     -> offset 5
        w[k][2] = q2.z;  // [2][2]     -> offset 10
        w[k][3] = q3.w;  // [3][3]     -> offset 15
    }

    // --- stream the output: BSUB float4 stores, coalesced across the wave ---
    float* outp = out + (long)n * 512 + e0 + (long)b0 * (N * D * S);
#pragma unroll 4
    for (int bl = 0; bl < BSUB; ++bl) {
        const float x0 = sx[bl][0], x1 = sx[bl][1], x2 = sx[bl][2], x3 = sx[bl][3];
        float4 v;
        v.x = w[0][0] * x0 + w[0][1] * x1 + w[0][2] * x2 + w[0][3] * x3;
        v.y = w[1][0] * x0 + w[1][1] * x1 + w[1][2] * x2 + w[1][3] * x3;
        v.z = w[2][0] * x0 + w[2][1] * x1 + w[2][2] * x2 + w[2][3] * x3;
        v.w = w[3][0] * x0 + w[3][1] * x1 + w[3][2] * x2 + w[3][3] * x3;
        *(float4*)(outp + (long)bl * (N * D * S)) = v;
    }
}

extern "C" void kernel_launch(void* const* d_in, const int* in_sizes, int n_in,
                              void* d_out, int out_size, void* d_ws, size_t ws_size,
                              hipStream_t stream) {
    const float* x     = (const float*)d_in[0];   // [64,1,128,128]
    const float* pesos = (const float*)d_in[1];   // [1024,16,32,4,4]
    float* out = (float*)d_out;                    // [64,1024,16,32]

    dim3 grid(N, BCHUNKS);
    conexao_regional_kernel<<<grid, 128, 0, stream>>>(x, pesos, out);
}

// Round 4
// 176.806 us; speedup vs baseline: 1.0730x; 1.0730x over previous
//
#include <hip/hip_runtime.h>

// Problem constants (from reference)
#define B 64
#define H 128
#define W 128
#define R 4
#define GW 32
#define N 1024
#define D 16
#define S 32
// One block per n, 128 threads, each thread owns 4 consecutive (d,s) elements.
// Pesos is read EXACTLY once (R2 showed b-splitting re-reads pesos at a net
// loss; R1 at 8 waves/CU already sat at the 134 MB write roofline).
// Output + pesos use nontemporal access: pure streaming, no reuse.
// NOTE: __builtin_nontemporal_* requires native clang vectors, not
// HIP_vector_type (float4) — hence vf4 below.

typedef float vf4 __attribute__((ext_vector_type(4)));

__global__ __launch_bounds__(128) void conexao_regional_kernel(
    const float* __restrict__ x,       // [B,1,H,W]
    const float* __restrict__ pesos,   // [N,D,S,R,R]
    float* __restrict__ out)           // [B,N,D,S]
{
    __shared__ float sx[B][R];  // patch diagonals for this block's n (1 KB)

    const int n   = blockIdx.x;
    const int tid = threadIdx.x;

    // --- stage xd[b][r] = x[b, 0, i*R+r, j*R+r] into LDS ---
    // flat addr: b*H*W + (i*R)*W + j*R + r*(W+1)
    const int i = n / GW, j = n % GW;
    const int xbase = i * (R * W) + j * R;
    for (int t = tid; t < B * R; t += 128) {
        const int b = t >> 2, r = t & 3;
        sx[b][r] = x[b * (H * W) + xbase + r * (W + 1)];
    }
    __syncthreads();

    // --- load weight diagonals for this thread's 4 elements (nontemporal) ---
    // pesos[n,d,s,:,:] is a contiguous 16-float (64 B) block at (n*512+e)*16;
    // diagonal elements sit at offsets 0, 5, 10, 15 within it.
    const int  e0    = tid * 4;                         // element in [0,512)
    const long pbase = ((long)n * 512 + e0) * 16;       // in floats
    float w[4][4];
#pragma unroll
    for (int k = 0; k < 4; ++k) {
        const vf4* p = (const vf4*)(pesos + pbase + (long)k * 16);
        const vf4 q0 = __builtin_nontemporal_load(p + 0);
        const vf4 q1 = __builtin_nontemporal_load(p + 1);
        const vf4 q2 = __builtin_nontemporal_load(p + 2);
        const vf4 q3 = __builtin_nontemporal_load(p + 3);
        w[k][0] = q0.x;  // [r=0][r=0] -> offset 0
        w[k][1] = q1.y;  // [1][1]     -> offset 5
        w[k][2] = q2.z;  // [2][2]     -> offset 10
        w[k][3] = q3.w;  // [3][3]     -> offset 15
    }

    // --- stream the output: 64 float4 nontemporal stores ---
    float* outp = out + (long)n * 512 + e0;
#pragma unroll 8
    for (int b = 0; b < B; ++b) {
        const vf4 xv = *(const vf4*)&sx[b][0];   // one ds_read_b128
        vf4 v;
        v.x = w[0][0] * xv.x + w[0][1] * xv.y + w[0][2] * xv.z + w[0][3] * xv.w;
        v.y = w[1][0] * xv.x + w[1][1] * xv.y + w[1][2] * xv.z + w[1][3] * xv.w;
        v.z = w[2][0] * xv.x + w[2][1] * xv.y + w[2][2] * xv.z + w[2][3] * xv.w;
        v.w = w[3][0] * xv.x + w[3][1] * xv.y + w[3][2] * xv.z + w[3][3] * xv.w;
        __builtin_nontemporal_store(v, (vf4*)(outp + (long)b * (N * D * S)));
    }
}

extern "C" void kernel_launch(void* const* d_in, const int* in_sizes, int n_in,
                              void* d_out, int out_size, void* d_ws, size_t ws_size,
                              hipStream_t stream) {
    const float* x     = (const float*)d_in[0];   // [64,1,128,128]
    const float* pesos = (const float*)d_in[1];   // [1024,16,32,4,4]
    float* out = (float*)d_out;                    // [64,1024,16,32]

    conexao_regional_kernel<<<N, 128, 0, stream>>>(x, pesos, out);
}